// Round 7
// baseline (129.806 us; speedup 1.0000x reference)
//
#include <hip/hip_runtime.h>

#define SUB   8
#define INCH  64
#define IMH   128
#define IMW   128
#define OUTCH 128
#define OH    126
#define OW    126

#define YT 8            // output rows per block
#define XT 16           // output cols per block
#define TR 10           // input rows staged (YT+2)
#define RS 20           // words per staged row (18 used + 2 pad)
#define NCH 39          // channels staged (32 owned + 7 halo)
#define CHS 204         // words per channel (10*20=200 + 4 pad)
#define LDS_WORDS (NCH * CHS)      // 7956 words = 31824 B -> 5 blocks/CU
#define LDS_VEC4  ((LDS_WORDS)/4)  // 1989
#define TRB 6           // input rows per y-half (4 out rows + 2)

// ---- weight prep: chunk c = s*64 + o0 (o0 in [0,64)): 20 floats, 16B aligned
//      t0..8  = W[o0][s][.][.],  t9..17 = W[o0+64][s][.][.]
__global__ __launch_bounds__(256)
void prep_weights_kernel(const float* __restrict__ Wg, float* __restrict__ Wp) {
    int idx = blockIdx.x * 256 + threadIdx.x;
    if (idx < 512 * 18) {
        int chunk = idx / 18;
        int t     = idx - chunk * 18;
        int s = chunk >> 6;
        int p = chunk & 63;
        int o  = (t < 9) ? p : p + 64;
        int tt = (t < 9) ? t : t - 9;
        Wp[chunk * 20 + t] = Wg[(o * SUB + s) * 9 + tt];
    }
}

// 128 threads: p(32 o-pairs) x yh(2) x xg(2 groups of 8 cols).
// Thread = 2 och x 4 rows x 8 cols = 64 accs; compute reads are b128-only.
// launch_bounds(128,2): VGPR cap 256 -> no spill (R2/R4/R5 lesson).
__global__ __launch_bounds__(128, 2)
void Group_Conv_84731114815961_kernel(const float* __restrict__ X,
                                      const float* __restrict__ Wg,
                                      const float* __restrict__ Bias,
                                      const float* __restrict__ Wp,
                                      float* __restrict__ Out) {
    __shared__ float xin[LDS_WORDS];   // 31824 B -> 5 blocks/CU (LDS-limited)

    const int tx = blockIdx.x;        // 0..7
    const int ty = blockIdx.y;        // 0..15
    const int h  = blockIdx.z & 1;    // channel half
    const int b  = blockIdx.z >> 1;   // batch
    const int x0 = tx * XT;
    const int y0 = ty * YT;
    const int tid = threadIdx.x;

    // ---- stage NCH channels x 10 rows x 20 cols (R6 pattern, 128 threads) ----
    const float* Xb = X + (size_t)b * INCH * IMH * IMW;
    #pragma unroll
    for (int it = 0; it < 16; ++it) {
        int k = it * 128 + tid;
        if (k < LDS_VEC4) {
            int cl  = k / 51;                 // 51 float4 per channel (204 words)
            int rem = k - cl * 51;
            int r   = rem / 5;                // 0..10 (10 = pad slot)
            int col = (rem - r * 5) * 4;      // 0,4,8,12,16
            int cg  = (h * 32 + cl) & 63;
            int sr = y0 + r;   if (sr > IMH - 1) sr = IMH - 1;
            int sc = x0 + col; if (sc > IMW - 4) sc = IMW - 4;
            const float4 v = *reinterpret_cast<const float4*>(Xb + (cg * IMH + sr) * IMW + sc);
            *reinterpret_cast<float4*>(&xin[k * 4]) = v;
        }
    }
    __syncthreads();

    const int p  = tid >> 2;          // 0..31  o-pair within half
    const int yh = (tid >> 1) & 1;    // y half (rows 4yh..4yh+3)
    const int xg = tid & 1;           // 8-col group
    const int cb = xg << 3;
    const int o0 = h * 32 + p;        // o1 = o0 + 64

    float acc0[4][8];
    float acc1[4][8];
    #pragma unroll
    for (int y = 0; y < 4; ++y)
        #pragma unroll
        for (int q = 0; q < 8; ++q) { acc0[y][q] = 0.f; acc1[y][q] = 0.f; }

    const bool useWp = (Wp != nullptr);

    for (int s = 0; s < SUB; ++s) {
        const int cl = p + s;         // 0..38 staged channel index
        float w0[9], w1[9];
        if (useWp) {
            const float4* wc = reinterpret_cast<const float4*>(Wp + ((s << 6) + o0) * 20);
            const float4 f0 = wc[0], f1 = wc[1], f2 = wc[2], f3 = wc[3], f4 = wc[4];
            w0[0]=f0.x; w0[1]=f0.y; w0[2]=f0.z; w0[3]=f0.w;
            w0[4]=f1.x; w0[5]=f1.y; w0[6]=f1.z; w0[7]=f1.w;
            w0[8]=f2.x;
            w1[0]=f2.y; w1[1]=f2.z; w1[2]=f2.w;
            w1[3]=f3.x; w1[4]=f3.y; w1[5]=f3.z; w1[6]=f3.w;
            w1[7]=f4.x; w1[8]=f4.y;
        } else {
            const float* w0p = Wg + (o0 * SUB + s) * 9;
            const float* w1p = Wg + ((o0 + 64) * SUB + s) * 9;
            #pragma unroll
            for (int t = 0; t < 9; ++t) { w0[t] = w0p[t]; w1[t] = w1p[t]; }
        }

        const float* base = &xin[cl * CHS + (yh << 2) * RS + cb];
        #pragma unroll
        for (int r = 0; r < TRB; ++r) {
            const float4 a0 = *reinterpret_cast<const float4*>(base + r * RS);
            const float4 a1 = *reinterpret_cast<const float4*>(base + r * RS + 4);
            const float4 a2 = *reinterpret_cast<const float4*>(base + r * RS + 8);
            const float v[12] = {a0.x, a0.y, a0.z, a0.w,
                                 a1.x, a1.y, a1.z, a1.w,
                                 a2.x, a2.y, a2.z, a2.w};
            #pragma unroll
            for (int i = 0; i < 3; ++i) {
                const int yo = r - i;
                if (yo >= 0 && yo < 4) {
                    #pragma unroll
                    for (int j = 0; j < 3; ++j) {
                        const float ww0 = w0[i * 3 + j];
                        const float ww1 = w1[i * 3 + j];
                        #pragma unroll
                        for (int q = 0; q < 8; ++q) {
                            acc0[yo][q] = fmaf(v[q + j], ww0, acc0[yo][q]);
                            acc1[yo][q] = fmaf(v[q + j], ww1, acc1[yo][q]);
                        }
                    }
                }
            }
        }
    }

    // ---- epilogue: bias + masked stores (two float4 per row per och) ----
    const float bz0 = Bias[o0];
    const float bz1 = Bias[o0 + 64];
    const int   xcol = x0 + cb;
    const int   yb   = y0 + (yh << 2);
    float* O0 = Out + (((size_t)b * OUTCH + o0)      * OH) * OW;
    float* O1 = Out + (((size_t)b * OUTCH + o0 + 64) * OH) * OW;

    #pragma unroll
    for (int y = 0; y < 4; ++y) {
        const int oy = yb + y;
        if (oy < OH) {
            float* o0p = O0 + oy * OW + xcol;
            float* o1p = O1 + oy * OW + xcol;
            // group 0: cols xcol..xcol+3
            if (xcol + 3 < OW) {
                *reinterpret_cast<float4*>(o0p) = make_float4(
                    acc0[y][0]+bz0, acc0[y][1]+bz0, acc0[y][2]+bz0, acc0[y][3]+bz0);
                *reinterpret_cast<float4*>(o1p) = make_float4(
                    acc1[y][0]+bz1, acc1[y][1]+bz1, acc1[y][2]+bz1, acc1[y][3]+bz1);
            } else {
                #pragma unroll
                for (int q = 0; q < 4; ++q) if (xcol + q < OW) {
                    o0p[q] = acc0[y][q] + bz0;
                    o1p[q] = acc1[y][q] + bz1;
                }
            }
            // group 1: cols xcol+4..xcol+7
            if (xcol + 7 < OW) {
                *reinterpret_cast<float4*>(o0p + 4) = make_float4(
                    acc0[y][4]+bz0, acc0[y][5]+bz0, acc0[y][6]+bz0, acc0[y][7]+bz0);
                *reinterpret_cast<float4*>(o1p + 4) = make_float4(
                    acc1[y][4]+bz1, acc1[y][5]+bz1, acc1[y][6]+bz1, acc1[y][7]+bz1);
            } else {
                #pragma unroll
                for (int q = 4; q < 8; ++q) if (xcol + q < OW) {
                    o0p[q] = acc0[y][q] + bz0;
                    o1p[q] = acc1[y][q] + bz1;
                }
            }
        }
    }
}

extern "C" void kernel_launch(void* const* d_in, const int* in_sizes, int n_in,
                              void* d_out, int out_size, void* d_ws, size_t ws_size,
                              hipStream_t stream) {
    const float* X    = (const float*)d_in[0];
    const float* Wg   = (const float*)d_in[1];
    const float* Bias = (const float*)d_in[2];
    float*       Out  = (float*)d_out;

    float* Wp = nullptr;
    if (d_ws && ws_size >= 512 * 20 * sizeof(float)) {
        Wp = (float*)d_ws;
        prep_weights_kernel<<<36, 256, 0, stream>>>(Wg, Wp);
    }

    dim3 grid(8, 16, 32);   // x-tiles, y-tiles, (batch x channel-half)
    Group_Conv_84731114815961_kernel<<<grid, 128, 0, stream>>>(X, Wg, Bias, Wp, Out);
}